// Round 6
// baseline (98.756 us; speedup 1.0000x reference)
//
#include <hip/hip_runtime.h>
#include <hip/hip_bf16.h>
#include <stdint.h>

#define N_ROWS 50000
#define D 384
#define K 8
#define BATCH 512
#define NEGO 128
#define NEDGE 1024
#define EPS_G 1e-4f

typedef float f32x4 __attribute__((ext_vector_type(4)));
typedef short bf16x8 __attribute__((ext_vector_type(8)));

__device__ __forceinline__ float wave_reduce_sum(float v) {
#pragma unroll
    for (int d = 1; d < 64; d <<= 1) v += __shfl_xor(v, d);
    return v;
}

static __device__ __forceinline__ uint16_t f2bfbits(float f) {
    __hip_bfloat16 h = __float2bfloat16(f);
    union { __hip_bfloat16 h; uint16_t u; } cv;
    cv.h = h;
    return cv.u;
}

// ---------------------------------------------------------------------------
// Kernel A: normalize virtual rows, G = Vn Vn^T + eps I, invert 8x8.
// ---------------------------------------------------------------------------
__global__ __launch_bounds__(64) void prep_kernel(const float* __restrict__ virt,
                                                  float* __restrict__ Vn,
                                                  float* __restrict__ Ginv) {
    __shared__ float Vs[K * D];
    __shared__ float Gs[K * K];
    int tid = threadIdx.x;
    for (int t = tid; t < K * D; t += 64) Vs[t] = virt[t];
    __syncthreads();
    for (int k = 0; k < K; ++k) {
        float ss = 0.f;
        for (int t = tid; t < D; t += 64) { float v = Vs[k * D + t]; ss += v * v; }
        ss = wave_reduce_sum(ss);
        float inv = 1.0f / sqrtf(ss + 1e-12f);
        for (int t = tid; t < D; t += 64) {
            float v = Vs[k * D + t] * inv;
            Vs[k * D + t] = v;
            Vn[k * D + t] = v;
        }
        __syncthreads();
    }
    int k = tid >> 3, m = tid & 7;
    float g = 0.f;
    for (int j = 0; j < D; ++j) g += Vs[k * D + j] * Vs[m * D + j];
    if (k == m) g += EPS_G;
    Gs[tid] = g;
    __syncthreads();
    if (tid == 0) {
        float A[K][K], I8[K][K];
        for (int a = 0; a < K; ++a)
            for (int b2 = 0; b2 < K; ++b2) {
                A[a][b2] = Gs[a * K + b2];
                I8[a][b2] = (a == b2) ? 1.f : 0.f;
            }
        for (int p = 0; p < K; ++p) {
            float piv = 1.0f / A[p][p];
            for (int j = 0; j < K; ++j) { A[p][j] *= piv; I8[p][j] *= piv; }
            for (int r = 0; r < K; ++r)
                if (r != p) {
                    float f = A[r][p];
                    for (int j = 0; j < K; ++j) {
                        A[r][j] -= f * A[p][j];
                        I8[r][j] -= f * I8[p][j];
                    }
                }
        }
        for (int a = 0; a < K; ++a)
            for (int b2 = 0; b2 < K; ++b2) Ginv[a * K + b2] = I8[a][b2];
    }
}

// ---------------------------------------------------------------------------
// Kernel B: projection removal + l2norm, bf16 out.
// R5 post-mortem: per-row V re-reads made the kernel LDS-instruction-bound
// (96 ds_read_b128 + 36 shuffle ds-ops per wave per 4 rows).
// Restructure:
//  - 4 rows per 16-lane group -> each V ds_read_b128 feeds 4 rows.
//  - rss computed algebraically: |x - V^T c|^2 = ss - c.pk - eps*|c|^2
//    (G*Ginv = I), so NO third pass and no r[6] live range.
//  - coef solve done block-wide via small LDS arrays (1 thread per (row,k)),
//    read back as broadcast ds_read_b128 -> no per-lane 8x8 matmul.
// 64 rows/block, grid ceil(50000/64)=782, tail rows clamped (stores guarded).
// ---------------------------------------------------------------------------
__global__ __launch_bounds__(256) void local_kernel(const float* __restrict__ emb,
                                                    const float* __restrict__ Vn,
                                                    const float* __restrict__ Ginv,
                                                    __hip_bfloat16* __restrict__ outb) {
    __shared__ float Vs[K * D];       // 12288 B
    __shared__ float Gs[K * K];       // Ginv
    __shared__ float pkL[64][10];     // per local row: pk[0..7], ss at [8]
    __shared__ float coefL[64][8];
    __shared__ float invrL[64];
    int tid = threadIdx.x;
    for (int t = tid; t < K * D; t += 256) Vs[t] = Vn[t];
    if (tid < K * K) Gs[tid] = Ginv[tid];
    __syncthreads();
    const f32x4* Vs4 = (const f32x4*)Vs;

    int q = tid & 15;
    int grp = tid >> 4;  // 0..15, each owns 4 rows
    int lrow0 = grp * 4;
    size_t row0 = (size_t)blockIdx.x * 64 + lrow0;

    // ---- pass 1: pk[r][k] = x_r . v_k, ss[r] = |x_r|^2 ----
    float pk[4][K];
    float ss4[4];
#pragma unroll
    for (int r = 0; r < 4; ++r) {
        ss4[r] = 0.f;
#pragma unroll
        for (int k = 0; k < K; ++k) pk[r][k] = 0.f;
    }
#pragma unroll
    for (int r = 0; r < 4; ++r) {
        size_t row = row0 + r;
        size_t rowc = row < N_ROWS ? row : (size_t)(N_ROWS - 1);
        const f32x4* xs = (const f32x4*)(emb + rowc * D);
#pragma unroll
        for (int t = 0; t < 6; ++t) {
            int j = q + 16 * t;
            f32x4 a = xs[j];
            ss4[r] += a.x * a.x + a.y * a.y + a.z * a.z + a.w * a.w;
#pragma unroll
            for (int k = 0; k < K; ++k) {
                f32x4 w = Vs4[k * 96 + j];
                pk[r][k] += a.x * w.x + a.y * w.y + a.z * w.z + a.w * w.w;
            }
        }
    }
#pragma unroll
    for (int d = 1; d < 16; d <<= 1) {
#pragma unroll
        for (int r = 0; r < 4; ++r) {
            ss4[r] += __shfl_xor(ss4[r], d);
#pragma unroll
            for (int k = 0; k < K; ++k) pk[r][k] += __shfl_xor(pk[r][k], d);
        }
    }
    if (q == 0) {
#pragma unroll
        for (int r = 0; r < 4; ++r) {
#pragma unroll
            for (int k = 0; k < K; ++k) pkL[lrow0 + r][k] = pk[r][k];
            pkL[lrow0 + r][8] = ss4[r];
        }
    }
    __syncthreads();

    // ---- solve phase: thread handles (lrow, k) pairs; 256 threads x 2 ----
#pragma unroll
    for (int it = 0; it < 2; ++it) {
        int lr = (tid >> 3) + 32 * it;
        int k = tid & 7;
        float pkr[K + 1];
#pragma unroll
        for (int m = 0; m <= K; ++m) pkr[m] = pkL[lr][m];
        float c = 0.f;
#pragma unroll
        for (int m = 0; m < K; ++m) c += pkr[m] * Gs[m * K + k];
        coefL[lr][k] = c;
        // rss contribution of this k: c_k*pk_k + eps*c_k^2
        float term = c * pkr[k] + EPS_G * c * c;
#pragma unroll
        for (int d = 1; d < 8; d <<= 1) term += __shfl_xor(term, d);
        if (k == 0) {
            float rss = pkr[8] - term;
            invrL[lr] = 1.0f / sqrtf(rss + 1e-12f);
        }
    }
    __syncthreads();

    // ---- pass 2: residual, scale, store bf16 ----
#pragma unroll
    for (int r = 0; r < 4; ++r) {
        int lr = lrow0 + r;
        size_t row = row0 + r;
        size_t rowc = row < N_ROWS ? row : (size_t)(N_ROWS - 1);
        const f32x4* xs = (const f32x4*)(emb + rowc * D);
        const f32x4* crow = (const f32x4*)&coefL[lr][0];
        f32x4 c0 = crow[0], c1 = crow[1];
        float cf[K] = {c0.x, c0.y, c0.z, c0.w, c1.x, c1.y, c1.z, c1.w};
        float invr = invrL[lr];
        bool ok = row < N_ROWS;
#pragma unroll
        for (int t = 0; t < 6; ++t) {
            int j = q + 16 * t;
            f32x4 a = xs[j];
#pragma unroll
            for (int k = 0; k < K; ++k) {
                f32x4 w = Vs4[k * 96 + j];
                a.x -= cf[k] * w.x; a.y -= cf[k] * w.y;
                a.z -= cf[k] * w.z; a.w -= cf[k] * w.w;
            }
            ushort4 p;
            p.x = f2bfbits(a.x * invr); p.y = f2bfbits(a.y * invr);
            p.z = f2bfbits(a.z * invr); p.w = f2bfbits(a.w * invr);
            if (ok) *reinterpret_cast<ushort4*>(outb + row * D + (size_t)j * 4) = p;
        }
    }
}

// ---------------------------------------------------------------------------
// Kernel C (MFMA): per ego-graph: gather X (bf16) into swizzled LDS,
// sim = X X^T via mfma_f32_16x16x32_bf16 (wave w owns rows 16w..16w+15),
// fused gumbel softmax + adjacency-bitmask diff + per-batch score.
// ---------------------------------------------------------------------------
__global__ __launch_bounds__(512) void batch_kernel(const __hip_bfloat16* __restrict__ localb,
                                                    const float* __restrict__ gumbel,
                                                    const int* __restrict__ idx_batch,
                                                    const int* __restrict__ edges_src,
                                                    const int* __restrict__ edges_dst,
                                                    float* __restrict__ scores) {
    __shared__ __hip_bfloat16 Xs[NEGO * D];  // 98304 B, swizzled
    __shared__ uint32_t adjmask[NEGO * 4];   // 2048 B
    __shared__ int idxs[NEGO];
    __shared__ float red[8];
    int tid = threadIdx.x;
    int b = blockIdx.x;
    if (tid < NEGO) idxs[tid] = idx_batch[b * NEGO + tid];
    adjmask[tid] = 0u;
    __syncthreads();

    {
        int row = tid >> 2, seg = tid & 3;
        const uint4* src = (const uint4*)(localb + (size_t)idxs[row] * D);
        char* dstbase = (char*)Xs;
#pragma unroll
        for (int i = 0; i < 12; ++i) {
            int c = seg + 4 * i;
            uint4 v = src[c];
            int off = (row * 768 + c * 16) ^ ((row & 7) << 4);
            *(uint4*)(dstbase + off) = v;
        }
    }
    for (int e = tid; e < NEDGE; e += 512) {
        int s = edges_src[b * NEDGE + e];
        int dd = edges_dst[b * NEDGE + e];
        atomicOr(&adjmask[s * 4 + (dd >> 5)], 1u << (dd & 31));
    }

    int w = tid >> 6, l = tid & 63;
    int c15 = l & 15, g4 = l >> 4;

    float gpre[4][8];
    {
        const float* gb = gumbel + (size_t)b * NEGO * NEGO;
#pragma unroll
        for (int reg = 0; reg < 4; ++reg) {
            int row = w * 16 + g4 * 4 + reg;
#pragma unroll
            for (int t = 0; t < 8; ++t) gpre[reg][t] = gb[row * NEGO + 16 * t + c15];
        }
    }
    __syncthreads();

    f32x4 acc[8];
#pragma unroll
    for (int t = 0; t < 8; ++t) acc[t] = (f32x4){0.f, 0.f, 0.f, 0.f};
    const char* xb = (const char*)Xs;
    int ar = w * 16 + c15;
    int aswz = (ar & 7) << 4;
    for (int ks = 0; ks < 12; ++ks) {
        int kbyte = ks * 64 + g4 * 16;
        bf16x8 afrag = *(const bf16x8*)(xb + ((ar * 768 + kbyte) ^ aswz));
#pragma unroll
        for (int t = 0; t < 8; ++t) {
            int br = t * 16 + c15;
            bf16x8 bfrag = *(const bf16x8*)(xb + ((br * 768 + kbyte) ^ ((br & 7) << 4)));
            acc[t] = __builtin_amdgcn_mfma_f32_16x16x32_bf16(afrag, bfrag, acc[t], 0, 0, 0);
        }
    }

    float wave_score = 0.f;
#pragma unroll
    for (int reg = 0; reg < 4; ++reg) {
        int row = w * 16 + g4 * 4 + reg;
        float z[8];
#pragma unroll
        for (int t = 0; t < 8; ++t) {
            float s = acc[t][reg];
            int col = 16 * t + c15;
            if (col == row) s = -1e9f;
            z[t] = s + gpre[reg][t];
        }
        float m = z[0];
#pragma unroll
        for (int t = 1; t < 8; ++t) m = fmaxf(m, z[t]);
#pragma unroll
        for (int d = 1; d < 16; d <<= 1) m = fmaxf(m, __shfl_xor(m, d));
        float e[8], se = 0.f;
#pragma unroll
        for (int t = 0; t < 8; ++t) { e[t] = expf(z[t] - m); se += e[t]; }
#pragma unroll
        for (int d = 1; d < 16; d <<= 1) se += __shfl_xor(se, d);
        float inv = 1.0f / se;
        uint32_t am[4];
#pragma unroll
        for (int qq = 0; qq < 4; ++qq) am[qq] = adjmask[row * 4 + qq];
        float sq = 0.f;
#pragma unroll
        for (int t = 0; t < 8; ++t) {
            int col = 16 * t + c15;
            float a = (float)((am[col >> 5] >> (col & 31)) & 1u);
            float d0 = a - e[t] * inv;
            sq += d0 * d0;
        }
#pragma unroll
        for (int d = 1; d < 16; d <<= 1) sq += __shfl_xor(sq, d);
        wave_score += sqrtf(sq);
    }
    wave_score += __shfl_xor(wave_score, 16);
    wave_score += __shfl_xor(wave_score, 32);
    if (l == 0) red[w] = wave_score;
    __syncthreads();
    if (tid == 0) {
        float tot = 0.f;
#pragma unroll
        for (int ww = 0; ww < 8; ++ww) tot += red[ww];
        scores[b] = tot * (1.0f / (float)NEGO);
    }
}

// ---------------------------------------------------------------------------
// Kernel D: min-max normalize scores, BCE loss.
// ---------------------------------------------------------------------------
__global__ __launch_bounds__(512) void finalize_kernel(const float* __restrict__ scores,
                                                       const int* __restrict__ labels,
                                                       float* __restrict__ out) {
    __shared__ float rmn[8], rmx[8], rsum[8];
    int tid = threadIdx.x, w = tid >> 6, l = tid & 63;
    float s = scores[tid];
    float mn = s, mx = s;
#pragma unroll
    for (int d = 1; d < 64; d <<= 1) {
        mn = fminf(mn, __shfl_xor(mn, d));
        mx = fmaxf(mx, __shfl_xor(mx, d));
    }
    if (l == 0) { rmn[w] = mn; rmx[w] = mx; }
    __syncthreads();
    mn = rmn[0]; mx = rmx[0];
#pragma unroll
    for (int ww = 1; ww < 8; ++ww) {
        mn = fminf(mn, rmn[ww]);
        mx = fmaxf(mx, rmx[ww]);
    }
    float norm = (s - mn) / (mx - mn + 1e-8f);
    out[tid] = norm;
    float y = (float)labels[tid];
    float lp = fmaxf(logf(norm), -100.0f);
    float l1p = fmaxf(log1pf(-norm), -100.0f);
    float term = y * lp + (1.0f - y) * l1p;
    term = wave_reduce_sum(term);
    if (l == 0) rsum[w] = term;
    __syncthreads();
    if (tid == 0) {
        float tot = 0.f;
        for (int ww = 0; ww < 8; ++ww) tot += rsum[ww];
        out[BATCH] = -tot / (float)BATCH;
    }
}

extern "C" void kernel_launch(void* const* d_in, const int* in_sizes, int n_in,
                              void* d_out, int out_size, void* d_ws, size_t ws_size,
                              hipStream_t stream) {
    (void)in_sizes; (void)n_in; (void)out_size; (void)ws_size;
    const float* text = (const float*)d_in[0];
    const float* virt = (const float*)d_in[1];
    const float* gum = (const float*)d_in[2];
    const int* idxb = (const int*)d_in[3];
    const int* esrc = (const int*)d_in[4];
    const int* edst = (const int*)d_in[5];
    const int* label = (const int*)d_in[6];
    float* out = (float*)d_out;

    float* Vn = (float*)d_ws;
    float* Ginv = Vn + K * D;
    float* scores = Ginv + K * K;
    __hip_bfloat16* localb = (__hip_bfloat16*)(scores + BATCH);

    hipLaunchKernelGGL(prep_kernel, dim3(1), dim3(64), 0, stream, virt, Vn, Ginv);
    hipLaunchKernelGGL(local_kernel, dim3((N_ROWS + 63) / 64), dim3(256), 0, stream, text, Vn, Ginv, localb);
    hipLaunchKernelGGL(batch_kernel, dim3(BATCH), dim3(512), 0, stream, localb, gum, idxb, esrc, edst, scores);
    hipLaunchKernelGGL(finalize_kernel, dim3(1), dim3(512), 0, stream, scores, label, out);
}

// Round 7
// 83.301 us; speedup vs baseline: 1.1855x; 1.1855x over previous
//
#include <hip/hip_runtime.h>
#include <hip/hip_bf16.h>
#include <stdint.h>

#define N_ROWS 50000
#define D 384
#define K 8
#define BATCH 512
#define NEGO 128
#define NEDGE 1024
#define EPS_G 1e-4f

typedef float f32x4 __attribute__((ext_vector_type(4)));
typedef short bf16x8 __attribute__((ext_vector_type(8)));

__device__ __forceinline__ float wave_reduce_sum(float v) {
#pragma unroll
    for (int d = 1; d < 64; d <<= 1) v += __shfl_xor(v, d);
    return v;
}

static __device__ __forceinline__ uint16_t f2bfbits(float f) {
    __hip_bfloat16 h = __float2bfloat16(f);
    union { __hip_bfloat16 h; uint16_t u; } cv;
    cv.h = h;
    return cv.u;
}

// ---------------------------------------------------------------------------
// Kernel A: normalize virtual rows, G = Vn Vn^T + eps I, invert 8x8.
// ---------------------------------------------------------------------------
__global__ __launch_bounds__(64) void prep_kernel(const float* __restrict__ virt,
                                                  float* __restrict__ Vn,
                                                  float* __restrict__ Ginv) {
    __shared__ float Vs[K * D];
    __shared__ float Gs[K * K];
    int tid = threadIdx.x;
    for (int t = tid; t < K * D; t += 64) Vs[t] = virt[t];
    __syncthreads();
    for (int k = 0; k < K; ++k) {
        float ss = 0.f;
        for (int t = tid; t < D; t += 64) { float v = Vs[k * D + t]; ss += v * v; }
        ss = wave_reduce_sum(ss);
        float inv = 1.0f / sqrtf(ss + 1e-12f);
        for (int t = tid; t < D; t += 64) {
            float v = Vs[k * D + t] * inv;
            Vs[k * D + t] = v;
            Vn[k * D + t] = v;
        }
        __syncthreads();
    }
    int k = tid >> 3, m = tid & 7;
    float g = 0.f;
    for (int j = 0; j < D; ++j) g += Vs[k * D + j] * Vs[m * D + j];
    if (k == m) g += EPS_G;
    Gs[tid] = g;
    __syncthreads();
    if (tid == 0) {
        float A[K][K], I8[K][K];
        for (int a = 0; a < K; ++a)
            for (int b2 = 0; b2 < K; ++b2) {
                A[a][b2] = Gs[a * K + b2];
                I8[a][b2] = (a == b2) ? 1.f : 0.f;
            }
        for (int p = 0; p < K; ++p) {
            float piv = 1.0f / A[p][p];
            for (int j = 0; j < K; ++j) { A[p][j] *= piv; I8[p][j] *= piv; }
            for (int r = 0; r < K; ++r)
                if (r != p) {
                    float f = A[r][p];
                    for (int j = 0; j < K; ++j) {
                        A[r][j] -= f * A[p][j];
                        I8[r][j] -= f * I8[p][j];
                    }
                }
        }
        for (int a = 0; a < K; ++a)
            for (int b2 = 0; b2 < K; ++b2) Ginv[a * K + b2] = I8[a][b2];
    }
}

// ---------------------------------------------------------------------------
// Kernel B: projection removal + l2norm, bf16 out.
// Operating point (R2/R3/R5 post-mortems): VGPR must stay <= ~96.
//  - 2 rows per 16-lane group: halves V ds_read_b128 per row vs R4 without
//    R5's register blowup (pk state = 16 VGPR).
//  - algebraic rss: |x - V^T c|^2 = ss - c.pk - eps|c|^2  -> no r[] live
//    range, pass 2 streams residual -> scale -> store.
//  - solve reads Ginv DIRECTLY from global with constant offsets (uniform
//    pointer -> s_load into SGPRs): removes R4's 128 uniform LDS reads/pair.
//  - pass 2 re-loads x (L3 hit); asm clobber stops CSE into live registers.
// ---------------------------------------------------------------------------
__global__ __launch_bounds__(256) void local_kernel(const float* __restrict__ emb,
                                                    const float* __restrict__ Vn,
                                                    const float* __restrict__ Ginv,
                                                    __hip_bfloat16* __restrict__ outb) {
    __shared__ float Vs[K * D];  // 12288 B
    int tid = threadIdx.x;
    for (int t = tid; t < K * D; t += 256) Vs[t] = Vn[t];
    __syncthreads();
    const f32x4* Vs4 = (const f32x4*)Vs;

    int q = tid & 15;
    int grp = tid >> 4;  // 0..15, each owns 2 rows
    size_t row0 = (size_t)blockIdx.x * 32 + grp * 2;
    size_t row1 = row0 + 1;
    bool ok0 = row0 < N_ROWS, ok1 = row1 < N_ROWS;
    const f32x4* x0 = (const f32x4*)(emb + (ok0 ? row0 : (size_t)(N_ROWS - 1)) * D);
    const f32x4* x1 = (const f32x4*)(emb + (ok1 ? row1 : (size_t)(N_ROWS - 1)) * D);

    // ---- pass 1: pk = x.v_k, ss = |x|^2 (chunks discarded) ----
    float pk0[K], pk1[K], ss0 = 0.f, ss1 = 0.f;
#pragma unroll
    for (int k = 0; k < K; ++k) { pk0[k] = 0.f; pk1[k] = 0.f; }
#pragma unroll
    for (int t = 0; t < 6; ++t) {
        int j = q + 16 * t;
        f32x4 a0 = x0[j], a1 = x1[j];
        ss0 += a0.x * a0.x + a0.y * a0.y + a0.z * a0.z + a0.w * a0.w;
        ss1 += a1.x * a1.x + a1.y * a1.y + a1.z * a1.z + a1.w * a1.w;
#pragma unroll
        for (int k = 0; k < K; ++k) {
            f32x4 w = Vs4[k * 96 + j];
            pk0[k] += a0.x * w.x + a0.y * w.y + a0.z * w.z + a0.w * w.w;
            pk1[k] += a1.x * w.x + a1.y * w.y + a1.z * w.z + a1.w * w.w;
        }
    }
#pragma unroll
    for (int d = 1; d < 16; d <<= 1) {
        ss0 += __shfl_xor(ss0, d);
        ss1 += __shfl_xor(ss1, d);
#pragma unroll
        for (int k = 0; k < K; ++k) {
            pk0[k] += __shfl_xor(pk0[k], d);
            pk1[k] += __shfl_xor(pk1[k], d);
        }
    }

    // ---- solve: c = Ginv pk (Ginv via scalar loads), rss algebraically ----
    float c0[K], c1[K];
    float dp0 = 0.f, dp1 = 0.f, n0 = 0.f, n1 = 0.f;
#pragma unroll
    for (int k = 0; k < K; ++k) {
        float a = 0.f, b2 = 0.f;
#pragma unroll
        for (int m = 0; m < K; ++m) {
            float g = Ginv[m * K + k];
            a += pk0[m] * g;
            b2 += pk1[m] * g;
        }
        c0[k] = a; c1[k] = b2;
        dp0 += a * pk0[k]; dp1 += b2 * pk1[k];
        n0 += a * a; n1 += b2 * b2;
    }
    float invr0 = 1.0f / sqrtf(ss0 - dp0 - EPS_G * n0 + 1e-12f);
    float invr1 = 1.0f / sqrtf(ss1 - dp1 - EPS_G * n1 + 1e-12f);

    // force re-load in pass 2 (no CSE back to long-lived registers)
    asm volatile("" ::: "memory");

    // ---- pass 2: residual, scale, store bf16 (streamed) ----
#pragma unroll
    for (int t = 0; t < 6; ++t) {
        int j = q + 16 * t;
        f32x4 a0 = x0[j], a1 = x1[j];
#pragma unroll
        for (int k = 0; k < K; ++k) {
            f32x4 w = Vs4[k * 96 + j];
            a0.x -= c0[k] * w.x; a0.y -= c0[k] * w.y;
            a0.z -= c0[k] * w.z; a0.w -= c0[k] * w.w;
            a1.x -= c1[k] * w.x; a1.y -= c1[k] * w.y;
            a1.z -= c1[k] * w.z; a1.w -= c1[k] * w.w;
        }
        ushort4 p0, p1;
        p0.x = f2bfbits(a0.x * invr0); p0.y = f2bfbits(a0.y * invr0);
        p0.z = f2bfbits(a0.z * invr0); p0.w = f2bfbits(a0.w * invr0);
        p1.x = f2bfbits(a1.x * invr1); p1.y = f2bfbits(a1.y * invr1);
        p1.z = f2bfbits(a1.z * invr1); p1.w = f2bfbits(a1.w * invr1);
        if (ok0) *reinterpret_cast<ushort4*>(outb + row0 * D + (size_t)j * 4) = p0;
        if (ok1) *reinterpret_cast<ushort4*>(outb + row1 * D + (size_t)j * 4) = p1;
    }
}

// ---------------------------------------------------------------------------
// Kernel C (MFMA): per ego-graph: gather X (bf16) into swizzled LDS,
// sim = X X^T via mfma_f32_16x16x32_bf16 (wave w owns rows 16w..16w+15),
// fused gumbel softmax + adjacency-bitmask diff + per-batch score.
// ---------------------------------------------------------------------------
__global__ __launch_bounds__(512) void batch_kernel(const __hip_bfloat16* __restrict__ localb,
                                                    const float* __restrict__ gumbel,
                                                    const int* __restrict__ idx_batch,
                                                    const int* __restrict__ edges_src,
                                                    const int* __restrict__ edges_dst,
                                                    float* __restrict__ scores) {
    __shared__ __hip_bfloat16 Xs[NEGO * D];  // 98304 B, swizzled
    __shared__ uint32_t adjmask[NEGO * 4];   // 2048 B
    __shared__ int idxs[NEGO];
    __shared__ float red[8];
    int tid = threadIdx.x;
    int b = blockIdx.x;
    if (tid < NEGO) idxs[tid] = idx_batch[b * NEGO + tid];
    adjmask[tid] = 0u;
    __syncthreads();

    {
        int row = tid >> 2, seg = tid & 3;
        const uint4* src = (const uint4*)(localb + (size_t)idxs[row] * D);
        char* dstbase = (char*)Xs;
#pragma unroll
        for (int i = 0; i < 12; ++i) {
            int c = seg + 4 * i;
            uint4 v = src[c];
            int off = (row * 768 + c * 16) ^ ((row & 7) << 4);
            *(uint4*)(dstbase + off) = v;
        }
    }
    for (int e = tid; e < NEDGE; e += 512) {
        int s = edges_src[b * NEDGE + e];
        int dd = edges_dst[b * NEDGE + e];
        atomicOr(&adjmask[s * 4 + (dd >> 5)], 1u << (dd & 31));
    }

    int w = tid >> 6, l = tid & 63;
    int c15 = l & 15, g4 = l >> 4;

    float gpre[4][8];
    {
        const float* gb = gumbel + (size_t)b * NEGO * NEGO;
#pragma unroll
        for (int reg = 0; reg < 4; ++reg) {
            int row = w * 16 + g4 * 4 + reg;
#pragma unroll
            for (int t = 0; t < 8; ++t) gpre[reg][t] = gb[row * NEGO + 16 * t + c15];
        }
    }
    __syncthreads();

    f32x4 acc[8];
#pragma unroll
    for (int t = 0; t < 8; ++t) acc[t] = (f32x4){0.f, 0.f, 0.f, 0.f};
    const char* xb = (const char*)Xs;
    int ar = w * 16 + c15;
    int aswz = (ar & 7) << 4;
    for (int ks = 0; ks < 12; ++ks) {
        int kbyte = ks * 64 + g4 * 16;
        bf16x8 afrag = *(const bf16x8*)(xb + ((ar * 768 + kbyte) ^ aswz));
#pragma unroll
        for (int t = 0; t < 8; ++t) {
            int br = t * 16 + c15;
            bf16x8 bfrag = *(const bf16x8*)(xb + ((br * 768 + kbyte) ^ ((br & 7) << 4)));
            acc[t] = __builtin_amdgcn_mfma_f32_16x16x32_bf16(afrag, bfrag, acc[t], 0, 0, 0);
        }
    }

    float wave_score = 0.f;
#pragma unroll
    for (int reg = 0; reg < 4; ++reg) {
        int row = w * 16 + g4 * 4 + reg;
        float z[8];
#pragma unroll
        for (int t = 0; t < 8; ++t) {
            float s = acc[t][reg];
            int col = 16 * t + c15;
            if (col == row) s = -1e9f;
            z[t] = s + gpre[reg][t];
        }
        float m = z[0];
#pragma unroll
        for (int t = 1; t < 8; ++t) m = fmaxf(m, z[t]);
#pragma unroll
        for (int d = 1; d < 16; d <<= 1) m = fmaxf(m, __shfl_xor(m, d));
        float e[8], se = 0.f;
#pragma unroll
        for (int t = 0; t < 8; ++t) { e[t] = expf(z[t] - m); se += e[t]; }
#pragma unroll
        for (int d = 1; d < 16; d <<= 1) se += __shfl_xor(se, d);
        float inv = 1.0f / se;
        uint32_t am[4];
#pragma unroll
        for (int qq = 0; qq < 4; ++qq) am[qq] = adjmask[row * 4 + qq];
        float sq = 0.f;
#pragma unroll
        for (int t = 0; t < 8; ++t) {
            int col = 16 * t + c15;
            float a = (float)((am[col >> 5] >> (col & 31)) & 1u);
            float d0 = a - e[t] * inv;
            sq += d0 * d0;
        }
#pragma unroll
        for (int d = 1; d < 16; d <<= 1) sq += __shfl_xor(sq, d);
        wave_score += sqrtf(sq);
    }
    wave_score += __shfl_xor(wave_score, 16);
    wave_score += __shfl_xor(wave_score, 32);
    if (l == 0) red[w] = wave_score;
    __syncthreads();
    if (tid == 0) {
        float tot = 0.f;
#pragma unroll
        for (int ww = 0; ww < 8; ++ww) tot += red[ww];
        scores[b] = tot * (1.0f / (float)NEGO);
    }
}

// ---------------------------------------------------------------------------
// Kernel D: min-max normalize scores, BCE loss.
// ---------------------------------------------------------------------------
__global__ __launch_bounds__(512) void finalize_kernel(const float* __restrict__ scores,
                                                       const int* __restrict__ labels,
                                                       float* __restrict__ out) {
    __shared__ float rmn[8], rmx[8], rsum[8];
    int tid = threadIdx.x, w = tid >> 6, l = tid & 63;
    float s = scores[tid];
    float mn = s, mx = s;
#pragma unroll
    for (int d = 1; d < 64; d <<= 1) {
        mn = fminf(mn, __shfl_xor(mn, d));
        mx = fmaxf(mx, __shfl_xor(mx, d));
    }
    if (l == 0) { rmn[w] = mn; rmx[w] = mx; }
    __syncthreads();
    mn = rmn[0]; mx = rmx[0];
#pragma unroll
    for (int ww = 1; ww < 8; ++ww) {
        mn = fminf(mn, rmn[ww]);
        mx = fmaxf(mx, rmx[ww]);
    }
    float norm = (s - mn) / (mx - mn + 1e-8f);
    out[tid] = norm;
    float y = (float)labels[tid];
    float lp = fmaxf(logf(norm), -100.0f);
    float l1p = fmaxf(log1pf(-norm), -100.0f);
    float term = y * lp + (1.0f - y) * l1p;
    term = wave_reduce_sum(term);
    if (l == 0) rsum[w] = term;
    __syncthreads();
    if (tid == 0) {
        float tot = 0.f;
        for (int ww = 0; ww < 8; ++ww) tot += rsum[ww];
        out[BATCH] = -tot / (float)BATCH;
    }
}

extern "C" void kernel_launch(void* const* d_in, const int* in_sizes, int n_in,
                              void* d_out, int out_size, void* d_ws, size_t ws_size,
                              hipStream_t stream) {
    (void)in_sizes; (void)n_in; (void)out_size; (void)ws_size;
    const float* text = (const float*)d_in[0];
    const float* virt = (const float*)d_in[1];
    const float* gum = (const float*)d_in[2];
    const int* idxb = (const int*)d_in[3];
    const int* esrc = (const int*)d_in[4];
    const int* edst = (const int*)d_in[5];
    const int* label = (const int*)d_in[6];
    float* out = (float*)d_out;

    float* Vn = (float*)d_ws;
    float* Ginv = Vn + K * D;
    float* scores = Ginv + K * K;
    __hip_bfloat16* localb = (__hip_bfloat16*)(scores + BATCH);

    hipLaunchKernelGGL(prep_kernel, dim3(1), dim3(64), 0, stream, virt, Vn, Ginv);
    hipLaunchKernelGGL(local_kernel, dim3((N_ROWS + 31) / 32), dim3(256), 0, stream, text, Vn, Ginv, localb);
    hipLaunchKernelGGL(batch_kernel, dim3(BATCH), dim3(512), 0, stream, localb, gum, idxb, esrc, edst, scores);
    hipLaunchKernelGGL(finalize_kernel, dim3(1), dim3(512), 0, stream, scores, label, out);
}

// Round 8
// 78.767 us; speedup vs baseline: 1.2538x; 1.0576x over previous
//
#include <hip/hip_runtime.h>
#include <hip/hip_bf16.h>
#include <stdint.h>

#define N_ROWS 50000
#define D 384
#define K 8
#define BATCH 512
#define NEGO 128
#define NEDGE 1024
#define EPS_G 1e-4f

typedef float f32x4 __attribute__((ext_vector_type(4)));
typedef short bf16x8 __attribute__((ext_vector_type(8)));

__device__ __forceinline__ float wave_reduce_sum(float v) {
#pragma unroll
    for (int d = 1; d < 64; d <<= 1) v += __shfl_xor(v, d);
    return v;
}

static __device__ __forceinline__ uint16_t f2bfbits(float f) {
    __hip_bfloat16 h = __float2bfloat16(f);
    union { __hip_bfloat16 h; uint16_t u; } cv;
    cv.h = h;
    return cv.u;
}

// ---------------------------------------------------------------------------
// Kernel A: normalize virtual rows, G = Vn Vn^T + eps I, invert 8x8.
// ---------------------------------------------------------------------------
__global__ __launch_bounds__(64) void prep_kernel(const float* __restrict__ virt,
                                                  float* __restrict__ Vn,
                                                  float* __restrict__ Ginv) {
    __shared__ float Vs[K * D];
    __shared__ float Gs[K * K];
    int tid = threadIdx.x;
    for (int t = tid; t < K * D; t += 64) Vs[t] = virt[t];
    __syncthreads();
    for (int k = 0; k < K; ++k) {
        float ss = 0.f;
        for (int t = tid; t < D; t += 64) { float v = Vs[k * D + t]; ss += v * v; }
        ss = wave_reduce_sum(ss);
        float inv = 1.0f / sqrtf(ss + 1e-12f);
        for (int t = tid; t < D; t += 64) {
            float v = Vs[k * D + t] * inv;
            Vs[k * D + t] = v;
            Vn[k * D + t] = v;
        }
        __syncthreads();
    }
    int k = tid >> 3, m = tid & 7;
    float g = 0.f;
    for (int j = 0; j < D; ++j) g += Vs[k * D + j] * Vs[m * D + j];
    if (k == m) g += EPS_G;
    Gs[tid] = g;
    __syncthreads();
    if (tid == 0) {
        float A[K][K], I8[K][K];
        for (int a = 0; a < K; ++a)
            for (int b2 = 0; b2 < K; ++b2) {
                A[a][b2] = Gs[a * K + b2];
                I8[a][b2] = (a == b2) ? 1.f : 0.f;
            }
        for (int p = 0; p < K; ++p) {
            float piv = 1.0f / A[p][p];
            for (int j = 0; j < K; ++j) { A[p][j] *= piv; I8[p][j] *= piv; }
            for (int r = 0; r < K; ++r)
                if (r != p) {
                    float f = A[r][p];
                    for (int j = 0; j < K; ++j) {
                        A[r][j] -= f * A[p][j];
                        I8[r][j] -= f * I8[p][j];
                    }
                }
        }
        for (int a = 0; a < K; ++a)
            for (int b2 = 0; b2 < K; ++b2) Ginv[a * K + b2] = I8[a][b2];
    }
}

// ---------------------------------------------------------------------------
// Kernel B: projection removal + l2norm, bf16 out.
// R4/R6 post-mortem: three structures all plateaued ~48us with occupancy
// 16-27% and VALUBusy ~25% -- latency-bound, few long-chained waves.
// D-SPLIT restructure: each row handled by 32 lanes (two 16-lane half-row
// groups in the SAME wave; lane owns 3 f32x4 chunks). Wave = 2 rows,
// block 256 = 8 rows, grid 6250 (4x more blocks than R6).
//  - xv[3] stays LIVE through the solve (12 regs) -> no pass-2 reload.
//  - reduce = 5 shfl_xor steps inside 32-lane halves (xor<=16 never
//    crosses the row boundary).
//  - rss algebraic: |x - V^T c|^2 = ss - c.pk - eps|c|^2.
//  - Ginv via uniform global loads (s_load), no LDS for the solve.
// Target: VGPR ~55 -> 8 waves/SIMD; halved per-wave critical path.
// ---------------------------------------------------------------------------
__global__ __launch_bounds__(256) void local_kernel(const float* __restrict__ emb,
                                                    const float* __restrict__ Vn,
                                                    const float* __restrict__ Ginv,
                                                    __hip_bfloat16* __restrict__ outb) {
    __shared__ float Vs[K * D];  // 12288 B
    int tid = threadIdx.x;
    for (int t = tid; t < K * D; t += 256) Vs[t] = Vn[t];
    __syncthreads();
    const f32x4* Vs4 = (const f32x4*)Vs;

    int l = tid & 63;
    int wv = tid >> 6;           // wave 0..3
    int q = l & 15;
    int half = (l >> 4) & 1;     // which half of the row
    int sub = l >> 5;            // row within wave
    size_t row = (size_t)blockIdx.x * 8 + wv * 2 + sub;
    bool ok = row < N_ROWS;
    const f32x4* xs = (const f32x4*)(emb + (ok ? row : (size_t)(N_ROWS - 1)) * D);
    int jbase = half * 48 + q;   // f32x4 index within row (96 per row)

    // ---- load 3 chunks (stay live), pk + ss ----
    f32x4 xv[3];
#pragma unroll
    for (int t = 0; t < 3; ++t) xv[t] = xs[jbase + 16 * t];

    float ss = 0.f;
    float pk[K];
#pragma unroll
    for (int k = 0; k < K; ++k) pk[k] = 0.f;
#pragma unroll
    for (int t = 0; t < 3; ++t) {
        f32x4 a = xv[t];
        int j = jbase + 16 * t;
        ss += a.x * a.x + a.y * a.y + a.z * a.z + a.w * a.w;
#pragma unroll
        for (int k = 0; k < K; ++k) {
            f32x4 w = Vs4[k * 96 + j];
            pk[k] += a.x * w.x + a.y * w.y + a.z * w.z + a.w * w.w;
        }
    }
    // ---- reduce across the 32 lanes of this row ----
#pragma unroll
    for (int d = 1; d < 32; d <<= 1) {
        ss += __shfl_xor(ss, d);
#pragma unroll
        for (int k = 0; k < K; ++k) pk[k] += __shfl_xor(pk[k], d);
    }

    // ---- solve c = Ginv pk (redundant per lane), algebraic rss ----
    float c[K];
    float dp = 0.f, n2 = 0.f;
#pragma unroll
    for (int k = 0; k < K; ++k) {
        float a = 0.f;
#pragma unroll
        for (int m = 0; m < K; ++m) a += pk[m] * Ginv[m * K + k];
        c[k] = a;
        dp += a * pk[k];
        n2 += a * a;
    }
    float invr = 1.0f / sqrtf(ss - dp - EPS_G * n2 + 1e-12f);

    // ---- residual from live xv, scale, store bf16 ----
#pragma unroll
    for (int t = 0; t < 3; ++t) {
        int j = jbase + 16 * t;
        f32x4 a = xv[t];
#pragma unroll
        for (int k = 0; k < K; ++k) {
            f32x4 w = Vs4[k * 96 + j];
            a.x -= c[k] * w.x; a.y -= c[k] * w.y;
            a.z -= c[k] * w.z; a.w -= c[k] * w.w;
        }
        ushort4 p;
        p.x = f2bfbits(a.x * invr); p.y = f2bfbits(a.y * invr);
        p.z = f2bfbits(a.z * invr); p.w = f2bfbits(a.w * invr);
        if (ok) *reinterpret_cast<ushort4*>(outb + row * D + (size_t)j * 4) = p;
    }
}

// ---------------------------------------------------------------------------
// Kernel C (MFMA): per ego-graph: gather X (bf16) into swizzled LDS,
// sim = X X^T via mfma_f32_16x16x32_bf16 (wave w owns rows 16w..16w+15),
// fused gumbel softmax + adjacency-bitmask diff + per-batch score.
// ---------------------------------------------------------------------------
__global__ __launch_bounds__(512) void batch_kernel(const __hip_bfloat16* __restrict__ localb,
                                                    const float* __restrict__ gumbel,
                                                    const int* __restrict__ idx_batch,
                                                    const int* __restrict__ edges_src,
                                                    const int* __restrict__ edges_dst,
                                                    float* __restrict__ scores) {
    __shared__ __hip_bfloat16 Xs[NEGO * D];  // 98304 B, swizzled
    __shared__ uint32_t adjmask[NEGO * 4];   // 2048 B
    __shared__ int idxs[NEGO];
    __shared__ float red[8];
    int tid = threadIdx.x;
    int b = blockIdx.x;
    if (tid < NEGO) idxs[tid] = idx_batch[b * NEGO + tid];
    adjmask[tid] = 0u;
    __syncthreads();

    {
        int row = tid >> 2, seg = tid & 3;
        const uint4* src = (const uint4*)(localb + (size_t)idxs[row] * D);
        char* dstbase = (char*)Xs;
#pragma unroll
        for (int i = 0; i < 12; ++i) {
            int c = seg + 4 * i;
            uint4 v = src[c];
            int off = (row * 768 + c * 16) ^ ((row & 7) << 4);
            *(uint4*)(dstbase + off) = v;
        }
    }
    for (int e = tid; e < NEDGE; e += 512) {
        int s = edges_src[b * NEDGE + e];
        int dd = edges_dst[b * NEDGE + e];
        atomicOr(&adjmask[s * 4 + (dd >> 5)], 1u << (dd & 31));
    }

    int w = tid >> 6, l = tid & 63;
    int c15 = l & 15, g4 = l >> 4;

    float gpre[4][8];
    {
        const float* gb = gumbel + (size_t)b * NEGO * NEGO;
#pragma unroll
        for (int reg = 0; reg < 4; ++reg) {
            int row = w * 16 + g4 * 4 + reg;
#pragma unroll
            for (int t = 0; t < 8; ++t) gpre[reg][t] = gb[row * NEGO + 16 * t + c15];
        }
    }
    __syncthreads();

    f32x4 acc[8];
#pragma unroll
    for (int t = 0; t < 8; ++t) acc[t] = (f32x4){0.f, 0.f, 0.f, 0.f};
    const char* xb = (const char*)Xs;
    int ar = w * 16 + c15;
    int aswz = (ar & 7) << 4;
    for (int ks = 0; ks < 12; ++ks) {
        int kbyte = ks * 64 + g4 * 16;
        bf16x8 afrag = *(const bf16x8*)(xb + ((ar * 768 + kbyte) ^ aswz));
#pragma unroll
        for (int t = 0; t < 8; ++t) {
            int br = t * 16 + c15;
            bf16x8 bfrag = *(const bf16x8*)(xb + ((br * 768 + kbyte) ^ ((br & 7) << 4)));
            acc[t] = __builtin_amdgcn_mfma_f32_16x16x32_bf16(afrag, bfrag, acc[t], 0, 0, 0);
        }
    }

    float wave_score = 0.f;
#pragma unroll
    for (int reg = 0; reg < 4; ++reg) {
        int row = w * 16 + g4 * 4 + reg;
        float z[8];
#pragma unroll
        for (int t = 0; t < 8; ++t) {
            float s = acc[t][reg];
            int col = 16 * t + c15;
            if (col == row) s = -1e9f;
            z[t] = s + gpre[reg][t];
        }
        float m = z[0];
#pragma unroll
        for (int t = 1; t < 8; ++t) m = fmaxf(m, z[t]);
#pragma unroll
        for (int d = 1; d < 16; d <<= 1) m = fmaxf(m, __shfl_xor(m, d));
        float e[8], se = 0.f;
#pragma unroll
        for (int t = 0; t < 8; ++t) { e[t] = expf(z[t] - m); se += e[t]; }
#pragma unroll
        for (int d = 1; d < 16; d <<= 1) se += __shfl_xor(se, d);
        float inv = 1.0f / se;
        uint32_t am[4];
#pragma unroll
        for (int qq = 0; qq < 4; ++qq) am[qq] = adjmask[row * 4 + qq];
        float sq = 0.f;
#pragma unroll
        for (int t = 0; t < 8; ++t) {
            int col = 16 * t + c15;
            float a = (float)((am[col >> 5] >> (col & 31)) & 1u);
            float d0 = a - e[t] * inv;
            sq += d0 * d0;
        }
#pragma unroll
        for (int d = 1; d < 16; d <<= 1) sq += __shfl_xor(sq, d);
        wave_score += sqrtf(sq);
    }
    wave_score += __shfl_xor(wave_score, 16);
    wave_score += __shfl_xor(wave_score, 32);
    if (l == 0) red[w] = wave_score;
    __syncthreads();
    if (tid == 0) {
        float tot = 0.f;
#pragma unroll
        for (int ww = 0; ww < 8; ++ww) tot += red[ww];
        scores[b] = tot * (1.0f / (float)NEGO);
    }
}

// ---------------------------------------------------------------------------
// Kernel D: min-max normalize scores, BCE loss.
// ---------------------------------------------------------------------------
__global__ __launch_bounds__(512) void finalize_kernel(const float* __restrict__ scores,
                                                       const int* __restrict__ labels,
                                                       float* __restrict__ out) {
    __shared__ float rmn[8], rmx[8], rsum[8];
    int tid = threadIdx.x, w = tid >> 6, l = tid & 63;
    float s = scores[tid];
    float mn = s, mx = s;
#pragma unroll
    for (int d = 1; d < 64; d <<= 1) {
        mn = fminf(mn, __shfl_xor(mn, d));
        mx = fmaxf(mx, __shfl_xor(mx, d));
    }
    if (l == 0) { rmn[w] = mn; rmx[w] = mx; }
    __syncthreads();
    mn = rmn[0]; mx = rmx[0];
#pragma unroll
    for (int ww = 1; ww < 8; ++ww) {
        mn = fminf(mn, rmn[ww]);
        mx = fmaxf(mx, rmx[ww]);
    }
    float norm = (s - mn) / (mx - mn + 1e-8f);
    out[tid] = norm;
    float y = (float)labels[tid];
    float lp = fmaxf(logf(norm), -100.0f);
    float l1p = fmaxf(log1pf(-norm), -100.0f);
    float term = y * lp + (1.0f - y) * l1p;
    term = wave_reduce_sum(term);
    if (l == 0) rsum[w] = term;
    __syncthreads();
    if (tid == 0) {
        float tot = 0.f;
        for (int ww = 0; ww < 8; ++ww) tot += rsum[ww];
        out[BATCH] = -tot / (float)BATCH;
    }
}

extern "C" void kernel_launch(void* const* d_in, const int* in_sizes, int n_in,
                              void* d_out, int out_size, void* d_ws, size_t ws_size,
                              hipStream_t stream) {
    (void)in_sizes; (void)n_in; (void)out_size; (void)ws_size;
    const float* text = (const float*)d_in[0];
    const float* virt = (const float*)d_in[1];
    const float* gum = (const float*)d_in[2];
    const int* idxb = (const int*)d_in[3];
    const int* esrc = (const int*)d_in[4];
    const int* edst = (const int*)d_in[5];
    const int* label = (const int*)d_in[6];
    float* out = (float*)d_out;

    float* Vn = (float*)d_ws;
    float* Ginv = Vn + K * D;
    float* scores = Ginv + K * K;
    __hip_bfloat16* localb = (__hip_bfloat16*)(scores + BATCH);

    hipLaunchKernelGGL(prep_kernel, dim3(1), dim3(64), 0, stream, virt, Vn, Ginv);
    hipLaunchKernelGGL(local_kernel, dim3((N_ROWS + 7) / 8), dim3(256), 0, stream, text, Vn, Ginv, localb);
    hipLaunchKernelGGL(batch_kernel, dim3(BATCH), dim3(512), 0, stream, localb, gum, idxb, esrc, edst, scores);
    hipLaunchKernelGGL(finalize_kernel, dim3(1), dim3(512), 0, stream, scores, label, out);
}

// Round 9
// 77.442 us; speedup vs baseline: 1.2752x; 1.0171x over previous
//
#include <hip/hip_runtime.h>
#include <hip/hip_bf16.h>
#include <stdint.h>

#define N_ROWS 50000
#define D 384
#define K 8
#define BATCH 512
#define NEGO 128
#define NEDGE 1024
#define EPS_G 1e-4f
#define LK_GRID 768  // persistent blocks for local_kernel (256 thr = 8 rows/iter)

typedef float f32x4 __attribute__((ext_vector_type(4)));
typedef short bf16x8 __attribute__((ext_vector_type(8)));

__device__ __forceinline__ float wave_reduce_sum(float v) {
#pragma unroll
    for (int d = 1; d < 64; d <<= 1) v += __shfl_xor(v, d);
    return v;
}

static __device__ __forceinline__ uint16_t f2bfbits(float f) {
    __hip_bfloat16 h = __float2bfloat16(f);
    union { __hip_bfloat16 h; uint16_t u; } cv;
    cv.h = h;
    return cv.u;
}

// ---------------------------------------------------------------------------
// Kernel A: normalize virtual rows, G = Vn Vn^T + eps I, invert 8x8.
// ---------------------------------------------------------------------------
__global__ __launch_bounds__(64) void prep_kernel(const float* __restrict__ virt,
                                                  float* __restrict__ Vn,
                                                  float* __restrict__ Ginv) {
    __shared__ float Vs[K * D];
    __shared__ float Gs[K * K];
    int tid = threadIdx.x;
    for (int t = tid; t < K * D; t += 64) Vs[t] = virt[t];
    __syncthreads();
    for (int k = 0; k < K; ++k) {
        float ss = 0.f;
        for (int t = tid; t < D; t += 64) { float v = Vs[k * D + t]; ss += v * v; }
        ss = wave_reduce_sum(ss);
        float inv = 1.0f / sqrtf(ss + 1e-12f);
        for (int t = tid; t < D; t += 64) {
            float v = Vs[k * D + t] * inv;
            Vs[k * D + t] = v;
            Vn[k * D + t] = v;
        }
        __syncthreads();
    }
    int k = tid >> 3, m = tid & 7;
    float g = 0.f;
    for (int j = 0; j < D; ++j) g += Vs[k * D + j] * Vs[m * D + j];
    if (k == m) g += EPS_G;
    Gs[tid] = g;
    __syncthreads();
    if (tid == 0) {
        float A[K][K], I8[K][K];
        for (int a = 0; a < K; ++a)
            for (int b2 = 0; b2 < K; ++b2) {
                A[a][b2] = Gs[a * K + b2];
                I8[a][b2] = (a == b2) ? 1.f : 0.f;
            }
        for (int p = 0; p < K; ++p) {
            float piv = 1.0f / A[p][p];
            for (int j = 0; j < K; ++j) { A[p][j] *= piv; I8[p][j] *= piv; }
            for (int r = 0; r < K; ++r)
                if (r != p) {
                    float f = A[r][p];
                    for (int j = 0; j < K; ++j) {
                        A[r][j] -= f * A[p][j];
                        I8[r][j] -= f * I8[p][j];
                    }
                }
        }
        for (int a = 0; a < K; ++a)
            for (int b2 = 0; b2 < K; ++b2) Ginv[a * K + b2] = I8[a][b2];
    }
}

// ---------------------------------------------------------------------------
// Kernel B: projection removal + l2norm, bf16 out.
// R7 post-mortem: the ~46us plateau across 4 structures was the LDS pipe --
// ~48 ds_read_b128 of V + 45 shuffle ds-ops per wave-iteration, ~21us/CU of
// serialized DS time. This version holds V IN REGISTERS (each lane needs only
// its 3 j-chunks x 8 k = 24 f32x4 = 96 VGPR), loaded once per persistent
// block from global (12KB, L2-resident), amortized over ~16 rows/wave via
// grid-stride. Zero __shared__, zero barriers; DS ops = reduction shuffles
// only. All V indices compile-time constant (no scratch).
// Row mapping (R7): 32 lanes per row (two 16-lane halves), wave = 2 rows,
// block 256 = 8 rows/iter, grid 768 -> stride 6144 rows, ~8 iters.
// ---------------------------------------------------------------------------
__global__ __launch_bounds__(256) void local_kernel(const float* __restrict__ emb,
                                                    const float* __restrict__ Vn,
                                                    const float* __restrict__ Ginv,
                                                    __hip_bfloat16* __restrict__ outb) {
    int tid = threadIdx.x;
    int l = tid & 63;
    int wv = tid >> 6;           // wave 0..3
    int q = l & 15;
    int half = (l >> 4) & 1;     // half of the row
    int sub = l >> 5;            // row within wave
    int jbase = half * 48 + q;   // f32x4 index within row (96 per row)

    // ---- V into registers: Vr[t][k] = V[k][jbase+16t] ----
    const f32x4* Vn4 = (const f32x4*)Vn;
    f32x4 Vr[3][8];
#pragma unroll
    for (int t = 0; t < 3; ++t)
#pragma unroll
        for (int k = 0; k < K; ++k) Vr[t][k] = Vn4[k * 96 + jbase + 16 * t];

    for (size_t row = (size_t)blockIdx.x * 8 + wv * 2 + sub; row < N_ROWS + 7;
         row += (size_t)LK_GRID * 8) {
        bool ok = row < N_ROWS;
        const f32x4* xs = (const f32x4*)(emb + (ok ? row : (size_t)(N_ROWS - 1)) * D);

        // ---- load 3 chunks (stay live), pk + ss ----
        f32x4 xv[3];
#pragma unroll
        for (int t = 0; t < 3; ++t) xv[t] = xs[jbase + 16 * t];

        float ss = 0.f;
        float pk[K];
#pragma unroll
        for (int k = 0; k < K; ++k) pk[k] = 0.f;
#pragma unroll
        for (int t = 0; t < 3; ++t) {
            f32x4 a = xv[t];
            ss += a.x * a.x + a.y * a.y + a.z * a.z + a.w * a.w;
#pragma unroll
            for (int k = 0; k < K; ++k) {
                f32x4 w = Vr[t][k];
                pk[k] += a.x * w.x + a.y * w.y + a.z * w.z + a.w * w.w;
            }
        }
        // ---- reduce across the 32 lanes of this row ----
#pragma unroll
        for (int d = 1; d < 32; d <<= 1) {
            ss += __shfl_xor(ss, d);
#pragma unroll
            for (int k = 0; k < K; ++k) pk[k] += __shfl_xor(pk[k], d);
        }

        // ---- solve c = Ginv pk (Ginv uniform -> scalar loads), algebraic rss ----
        float c[K];
        float dp = 0.f, n2 = 0.f;
#pragma unroll
        for (int k = 0; k < K; ++k) {
            float a = 0.f;
#pragma unroll
            for (int m = 0; m < K; ++m) a += pk[m] * Ginv[m * K + k];
            c[k] = a;
            dp += a * pk[k];
            n2 += a * a;
        }
        float invr = 1.0f / sqrtf(ss - dp - EPS_G * n2 + 1e-12f);

        // ---- residual from live xv + register V, scale, store bf16 ----
#pragma unroll
        for (int t = 0; t < 3; ++t) {
            f32x4 a = xv[t];
#pragma unroll
            for (int k = 0; k < K; ++k) {
                f32x4 w = Vr[t][k];
                a.x -= c[k] * w.x; a.y -= c[k] * w.y;
                a.z -= c[k] * w.z; a.w -= c[k] * w.w;
            }
            ushort4 p;
            p.x = f2bfbits(a.x * invr); p.y = f2bfbits(a.y * invr);
            p.z = f2bfbits(a.z * invr); p.w = f2bfbits(a.w * invr);
            if (ok)
                *reinterpret_cast<ushort4*>(outb + row * D + (size_t)(jbase + 16 * t) * 4) = p;
        }
    }
}

// ---------------------------------------------------------------------------
// Kernel C (MFMA): per ego-graph: gather X (bf16) into swizzled LDS,
// sim = X X^T via mfma_f32_16x16x32_bf16 (wave w owns rows 16w..16w+15),
// fused gumbel softmax + adjacency-bitmask diff + per-batch score.
// ---------------------------------------------------------------------------
__global__ __launch_bounds__(512) void batch_kernel(const __hip_bfloat16* __restrict__ localb,
                                                    const float* __restrict__ gumbel,
                                                    const int* __restrict__ idx_batch,
                                                    const int* __restrict__ edges_src,
                                                    const int* __restrict__ edges_dst,
                                                    float* __restrict__ scores) {
    __shared__ __hip_bfloat16 Xs[NEGO * D];  // 98304 B, swizzled
    __shared__ uint32_t adjmask[NEGO * 4];   // 2048 B
    __shared__ int idxs[NEGO];
    __shared__ float red[8];
    int tid = threadIdx.x;
    int b = blockIdx.x;
    if (tid < NEGO) idxs[tid] = idx_batch[b * NEGO + tid];
    adjmask[tid] = 0u;
    __syncthreads();

    {
        int row = tid >> 2, seg = tid & 3;
        const uint4* src = (const uint4*)(localb + (size_t)idxs[row] * D);
        char* dstbase = (char*)Xs;
#pragma unroll
        for (int i = 0; i < 12; ++i) {
            int c = seg + 4 * i;
            uint4 v = src[c];
            int off = (row * 768 + c * 16) ^ ((row & 7) << 4);
            *(uint4*)(dstbase + off) = v;
        }
    }
    for (int e = tid; e < NEDGE; e += 512) {
        int s = edges_src[b * NEDGE + e];
        int dd = edges_dst[b * NEDGE + e];
        atomicOr(&adjmask[s * 4 + (dd >> 5)], 1u << (dd & 31));
    }

    int w = tid >> 6, l = tid & 63;
    int c15 = l & 15, g4 = l >> 4;

    float gpre[4][8];
    {
        const float* gb = gumbel + (size_t)b * NEGO * NEGO;
#pragma unroll
        for (int reg = 0; reg < 4; ++reg) {
            int row = w * 16 + g4 * 4 + reg;
#pragma unroll
            for (int t = 0; t < 8; ++t) gpre[reg][t] = gb[row * NEGO + 16 * t + c15];
        }
    }
    __syncthreads();

    f32x4 acc[8];
#pragma unroll
    for (int t = 0; t < 8; ++t) acc[t] = (f32x4){0.f, 0.f, 0.f, 0.f};
    const char* xb = (const char*)Xs;
    int ar = w * 16 + c15;
    int aswz = (ar & 7) << 4;
    for (int ks = 0; ks < 12; ++ks) {
        int kbyte = ks * 64 + g4 * 16;
        bf16x8 afrag = *(const bf16x8*)(xb + ((ar * 768 + kbyte) ^ aswz));
#pragma unroll
        for (int t = 0; t < 8; ++t) {
            int br = t * 16 + c15;
            bf16x8 bfrag = *(const bf16x8*)(xb + ((br * 768 + kbyte) ^ ((br & 7) << 4)));
            acc[t] = __builtin_amdgcn_mfma_f32_16x16x32_bf16(afrag, bfrag, acc[t], 0, 0, 0);
        }
    }

    float wave_score = 0.f;
#pragma unroll
    for (int reg = 0; reg < 4; ++reg) {
        int row = w * 16 + g4 * 4 + reg;
        float z[8];
#pragma unroll
        for (int t = 0; t < 8; ++t) {
            float s = acc[t][reg];
            int col = 16 * t + c15;
            if (col == row) s = -1e9f;
            z[t] = s + gpre[reg][t];
        }
        float m = z[0];
#pragma unroll
        for (int t = 1; t < 8; ++t) m = fmaxf(m, z[t]);
#pragma unroll
        for (int d = 1; d < 16; d <<= 1) m = fmaxf(m, __shfl_xor(m, d));
        float e[8], se = 0.f;
#pragma unroll
        for (int t = 0; t < 8; ++t) { e[t] = expf(z[t] - m); se += e[t]; }
#pragma unroll
        for (int d = 1; d < 16; d <<= 1) se += __shfl_xor(se, d);
        float inv = 1.0f / se;
        uint32_t am[4];
#pragma unroll
        for (int qq = 0; qq < 4; ++qq) am[qq] = adjmask[row * 4 + qq];
        float sq = 0.f;
#pragma unroll
        for (int t = 0; t < 8; ++t) {
            int col = 16 * t + c15;
            float a = (float)((am[col >> 5] >> (col & 31)) & 1u);
            float d0 = a - e[t] * inv;
            sq += d0 * d0;
        }
#pragma unroll
        for (int d = 1; d < 16; d <<= 1) sq += __shfl_xor(sq, d);
        wave_score += sqrtf(sq);
    }
    wave_score += __shfl_xor(wave_score, 16);
    wave_score += __shfl_xor(wave_score, 32);
    if (l == 0) red[w] = wave_score;
    __syncthreads();
    if (tid == 0) {
        float tot = 0.f;
#pragma unroll
        for (int ww = 0; ww < 8; ++ww) tot += red[ww];
        scores[b] = tot * (1.0f / (float)NEGO);
    }
}

// ---------------------------------------------------------------------------
// Kernel D: min-max normalize scores, BCE loss.
// ---------------------------------------------------------------------------
__global__ __launch_bounds__(512) void finalize_kernel(const float* __restrict__ scores,
                                                       const int* __restrict__ labels,
                                                       float* __restrict__ out) {
    __shared__ float rmn[8], rmx[8], rsum[8];
    int tid = threadIdx.x, w = tid >> 6, l = tid & 63;
    float s = scores[tid];
    float mn = s, mx = s;
#pragma unroll
    for (int d = 1; d < 64; d <<= 1) {
        mn = fminf(mn, __shfl_xor(mn, d));
        mx = fmaxf(mx, __shfl_xor(mx, d));
    }
    if (l == 0) { rmn[w] = mn; rmx[w] = mx; }
    __syncthreads();
    mn = rmn[0]; mx = rmx[0];
#pragma unroll
    for (int ww = 1; ww < 8; ++ww) {
        mn = fminf(mn, rmn[ww]);
        mx = fmaxf(mx, rmx[ww]);
    }
    float norm = (s - mn) / (mx - mn + 1e-8f);
    out[tid] = norm;
    float y = (float)labels[tid];
    float lp = fmaxf(logf(norm), -100.0f);
    float l1p = fmaxf(log1pf(-norm), -100.0f);
    float term = y * lp + (1.0f - y) * l1p;
    term = wave_reduce_sum(term);
    if (l == 0) rsum[w] = term;
    __syncthreads();
    if (tid == 0) {
        float tot = 0.f;
        for (int ww = 0; ww < 8; ++ww) tot += rsum[ww];
        out[BATCH] = -tot / (float)BATCH;
    }
}

extern "C" void kernel_launch(void* const* d_in, const int* in_sizes, int n_in,
                              void* d_out, int out_size, void* d_ws, size_t ws_size,
                              hipStream_t stream) {
    (void)in_sizes; (void)n_in; (void)out_size; (void)ws_size;
    const float* text = (const float*)d_in[0];
    const float* virt = (const float*)d_in[1];
    const float* gum = (const float*)d_in[2];
    const int* idxb = (const int*)d_in[3];
    const int* esrc = (const int*)d_in[4];
    const int* edst = (const int*)d_in[5];
    const int* label = (const int*)d_in[6];
    float* out = (float*)d_out;

    float* Vn = (float*)d_ws;
    float* Ginv = Vn + K * D;
    float* scores = Ginv + K * K;
    __hip_bfloat16* localb = (__hip_bfloat16*)(scores + BATCH);

    hipLaunchKernelGGL(prep_kernel, dim3(1), dim3(64), 0, stream, virt, Vn, Ginv);
    hipLaunchKernelGGL(local_kernel, dim3(LK_GRID), dim3(256), 0, stream, text, Vn, Ginv, localb);
    hipLaunchKernelGGL(batch_kernel, dim3(BATCH), dim3(512), 0, stream, localb, gum, idxb, esrc, edst, scores);
    hipLaunchKernelGGL(finalize_kernel, dim3(1), dim3(512), 0, stream, scores, label, out);
}